// Round 5
// baseline (272.248 us; speedup 1.0000x reference)
//
#include <hip/hip_runtime.h>
#include <hip/hip_bf16.h>
#include <math.h>

// Problem constants (fixed by setup_inputs)
#define M_TOTAL 6272   // B*P
#define N_CS    16384  // coreset rows
#define D_DIM   384
#define BATCH   8
#define P_PATCH 784
#define KNN     9

// R14: 8-phase deep-pipelined GEMM (T3+T4+T5 port of the verified 256^2
// template). Tile 256cs x 128patch, BK=64, 8 waves (512 thr, 4x2 grid of
// 64x64), double-buffered 96KB LDS, 1 block/CU. R13's m97-structure hit its
// documented ceiling (MfmaUtil 33% ~= m98's 37%); R9/R10 proved coarse
// scheduling changes are null there. Per K-tile: 4 phases of {ds_read
// subtile; issue 2 gload_lds of t+1; s_barrier; lgkmcnt(0); sched_barrier;
// setprio(1); 8 MFMA; setprio(0); barrier}; ONE vmcnt(0) per K-tile after
// 3 phases of flight (issue-early/drain-late).
// Operand layout (VERIFIED in R13, absmax=0): A=coreset rows, C[n][m] with
// n in-lane -> epilogue is 16 in-lane compares + 2 shuffle rounds.
// launch_bounds law (R6/R11/R12): total(VGPR+AGPR) cap = 512/arg2(waves/EU).
// (512,2) -> 256 cap; need ~150. DO NOT raise arg2.
#define MTILES  (M_TOTAL / 128)  // 49 patch tiles
#define NTILES2 (N_CS / 256)     // 64 cs tiles -> pvals[m][64]
#define NBLK    (M_TOTAL / 4)    // 1568 reduce blocks; 784=4*196 -> one batch/block
#define PBB     196              // partial entries per batch

typedef _Float16 half8 __attribute__((ext_vector_type(8)));
typedef float    floatx4 __attribute__((ext_vector_type(4)));

// async global->LDS, 16B per lane; LDS dest must be uniform-base + lane*16
__device__ __forceinline__ void async_copy16(const void* g, void* l) {
    __builtin_amdgcn_global_load_lds(
        (const __attribute__((address_space(1))) void*)g,
        (__attribute__((address_space(3))) void*)l, 16, 0, 0);
}

__device__ __forceinline__ unsigned long long shfl_xor_u64(unsigned long long v, int mk) {
    int lo = __shfl_xor((int)(unsigned)v, mk, 64);
    int hi = __shfl_xor((int)(unsigned)(v >> 32), mk, 64);
    return ((unsigned long long)(unsigned)hi << 32) | (unsigned)lo;
}

// ---------------- convert fp32->f16, fused cs+emb (wave per row) ----------
__global__ void convert_all_kernel(const float* __restrict__ emb,
                                   const float* __restrict__ cs,
                                   _Float16* __restrict__ embh,
                                   _Float16* __restrict__ csh,
                                   float* __restrict__ cnorm) {
    int w = threadIdx.x >> 6, lane = threadIdx.x & 63;
    int row = blockIdx.x * 4 + w;
    if (row >= N_CS + M_TOTAL) return;
    bool is_cs = row < N_CS;
    const float* r = (is_cs ? cs + (size_t)row * D_DIM
                            : emb + (size_t)(row - N_CS) * D_DIM) + lane * 6;
    float2 a = *(const float2*)r;
    float2 b = *(const float2*)(r + 2);
    float2 c = *(const float2*)(r + 4);
    union { _Float16 h[2]; unsigned u; } p0, p1, p2;
    p0.h[0] = (_Float16)a.x; p0.h[1] = (_Float16)a.y;
    p1.h[0] = (_Float16)b.x; p1.h[1] = (_Float16)b.y;
    p2.h[0] = (_Float16)c.x; p2.h[1] = (_Float16)c.y;
    unsigned* dst = (unsigned*)(is_cs ? csh + (size_t)row * D_DIM
                                      : embh + (size_t)(row - N_CS) * D_DIM) + lane * 3;
    dst[0] = p0.u; dst[1] = p1.u; dst[2] = p2.u;
    if (is_cs) {
        float s = a.x * a.x + a.y * a.y + b.x * b.x + b.y * b.y + c.x * c.x + c.y * c.y;
#pragma unroll
        for (int mk = 1; mk <= 32; mk <<= 1) s += __shfl_xor(s, mk, 64);
        if (lane == 0) cnorm[row] = s;
    }
}

// --------------------------------------------- MFMA GEMM + min/argmin ----
// XCD partition: XCD x owns cs tiles by = x*8..x*8+7 (1.5MB csh slice
// L2-resident across all 49 patch tiles). LDS rows 128B; XOR-swizzle 16B
// chunks p = logical ^ (row&7); staged via pre-swizzled GLOBAL source with
// linear LDS dest, read back with the same XOR (both-sides rule).
__global__ __launch_bounds__(512, 2) void mindist_mfma_kernel(
    const _Float16* __restrict__ embh, const _Float16* __restrict__ csh,
    const float* __restrict__ cnorm,
    float* __restrict__ pvals, int* __restrict__ pidx) {
    __shared__ _Float16 As0[256 * 64];   // 32 KB (cs rows, buf 0)
    __shared__ _Float16 As1[256 * 64];   // 32 KB (cs rows, buf 1)
    __shared__ _Float16 Bs0[128 * 64];   // 16 KB (patch rows, buf 0)
    __shared__ _Float16 Bs1[128 * 64];   // 16 KB (patch rows, buf 1)
    __shared__ float smv[128 * 4];
    __shared__ int   smi[128 * 4];

    const int b    = blockIdx.x;
    const int bx   = b >> 6;                             // 0..48 patch tile
    const int by   = ((b & 7) << 3) | ((b >> 3) & 7);    // 0..63 cs tile, XCD-sliced
    const int tid  = threadIdx.x;
    const int lane = tid & 63;
    const int w    = tid >> 6;            // 0..7
    const int wr   = w >> 1;              // 0..3 cs quarter (64 rows)
    const int wc   = w & 1;               // 0..1 patch half (64 cols)
    const int prow0 = bx * 128;           // patch base
    const int nbase = by * 256;           // coreset base
    const int q   = lane >> 4;
    const int cl  = lane & 15;
    const int xsw = cl & 7;               // ds_read swizzle key (row&7)

    floatx4 acc[4][4];
#pragma unroll
    for (int mi = 0; mi < 4; ++mi)
#pragma unroll
        for (int nj = 0; nj < 4; ++nj) acc[mi][nj] = (floatx4){0.f, 0.f, 0.f, 0.f};

    // staging geometry: one gload_lds inst covers 8 rows (8 lanes/row);
    // source column chunk pre-swizzled so linear LDS == swizzled layout.
    const int srow = lane >> 3;                       // 0..7 row within inst
    const int scol = ((lane & 7) ^ srow) * 8;         // f16 col offset 0..56

    // A: 32 insts (4/wave), B: 16 insts (2/wave) per K-tile
#define STAGE_A(AS, KK, i)                                                    \
    async_copy16(csh + (size_t)(nbase + (w * 4 + (i)) * 8 + srow) * D_DIM     \
                     + (KK) + scol,                                           \
                 &AS[(w * 4 + (i)) * 512 + lane * 8])
#define STAGE_B(BS, KK, i)                                                    \
    async_copy16(embh + (size_t)(prow0 + (w * 2 + (i)) * 8 + srow) * D_DIM    \
                      + (KK) + scol,                                          \
                 &BS[(w * 2 + (i)) * 512 + lane * 8])

#define PH_BAR()                                                              \
    do {                                                                      \
        asm volatile("" ::: "memory");                                        \
        __builtin_amdgcn_s_barrier();                                         \
        asm volatile("" ::: "memory");                                        \
    } while (0)
#define LGKM0()  asm volatile("s_waitcnt lgkmcnt(0)" ::: "memory")
#define WAITV0() asm volatile("s_waitcnt vmcnt(0)" ::: "memory")

#define MFMA1(d, a, bb) d = __builtin_amdgcn_mfma_f32_16x16x32_f16(a, bb, d, 0, 0, 0)

    // one phase: ds_read subtile, issue stage portion, barrier, 8 MFMAs.
    // (nh==0 phases also load the 4 A fragments for this ks; af persist.)
#define PHASE(AC, BC, ks, nh, STG, TAILW)                                     \
    {                                                                         \
        if ((nh) == 0) {                                                      \
            af0 = *(const half8*)&AC[(wr * 64 +  0 + cl) * 64 + ((((ks) * 4 + q) ^ xsw)) * 8]; \
            af1 = *(const half8*)&AC[(wr * 64 + 16 + cl) * 64 + ((((ks) * 4 + q) ^ xsw)) * 8]; \
            af2 = *(const half8*)&AC[(wr * 64 + 32 + cl) * 64 + ((((ks) * 4 + q) ^ xsw)) * 8]; \
            af3 = *(const half8*)&AC[(wr * 64 + 48 + cl) * 64 + ((((ks) * 4 + q) ^ xsw)) * 8]; \
        }                                                                     \
        half8 bf0 = *(const half8*)&BC[(wc * 64 + (nh) * 32 +  0 + cl) * 64 + ((((ks) * 4 + q) ^ xsw)) * 8]; \
        half8 bf1 = *(const half8*)&BC[(wc * 64 + (nh) * 32 + 16 + cl) * 64 + ((((ks) * 4 + q) ^ xsw)) * 8]; \
        STG;                                                                  \
        PH_BAR();                                                             \
        LGKM0();                                                              \
        __builtin_amdgcn_sched_barrier(0);                                    \
        __builtin_amdgcn_s_setprio(1);                                        \
        MFMA1(acc[0][(nh) * 2], af0, bf0); MFMA1(acc[0][(nh) * 2 + 1], af0, bf1); \
        MFMA1(acc[1][(nh) * 2], af1, bf0); MFMA1(acc[1][(nh) * 2 + 1], af1, bf1); \
        MFMA1(acc[2][(nh) * 2], af2, bf0); MFMA1(acc[2][(nh) * 2 + 1], af2, bf1); \
        MFMA1(acc[3][(nh) * 2], af3, bf0); MFMA1(acc[3][(nh) * 2 + 1], af3, bf1); \
        __builtin_amdgcn_s_setprio(0);                                        \
        TAILW;                                                                \
        PH_BAR();                                                             \
    }

#define KTILE(AC, BC, S0, S1, S2, WV)                                         \
    {                                                                         \
        half8 af0, af1, af2, af3;                                             \
        PHASE(AC, BC, 0, 0, S0, {});                                          \
        PHASE(AC, BC, 0, 1, S1, {});                                          \
        PHASE(AC, BC, 1, 0, S2, {});                                          \
        PHASE(AC, BC, 1, 1, {},  WV);                                         \
    }

    // prologue: stage K-tile 0 into buf0, drain once
    STAGE_A(As0, 0, 0); STAGE_A(As0, 0, 1); STAGE_A(As0, 0, 2); STAGE_A(As0, 0, 3);
    STAGE_B(Bs0, 0, 0); STAGE_B(Bs0, 0, 1);
    WAITV0();
    __syncthreads();

    // 6 K-tiles of 64; tiles 0..4 prefetch t+1 across their phases, the
    // single vmcnt(0) per tile lands after ~3 MFMA phases of flight.
#pragma unroll 1
    for (int t = 0; t < 5; ++t) {
        const int kn = (t + 1) * 64;
        const _Float16* AC = (t & 1) ? As1 : As0;
        const _Float16* BC = (t & 1) ? Bs1 : Bs0;
        _Float16* AN = (t & 1) ? As0 : As1;
        _Float16* BN = (t & 1) ? Bs0 : Bs1;
        KTILE(AC, BC,
              { STAGE_A(AN, kn, 0); STAGE_A(AN, kn, 1); },
              { STAGE_A(AN, kn, 2); STAGE_A(AN, kn, 3); },
              { STAGE_B(BN, kn, 0); STAGE_B(BN, kn, 1); },
              WAITV0());
    }
    // tail: K-tile 5 lives in buf1, nothing left to stage
    KTILE(As1, Bs1, {}, {}, {}, {});

#undef KTILE
#undef PHASE
#undef MFMA1
#undef STAGE_A
#undef STAGE_B

    // epilogue (R13-verified layout): per patch col, min over this wave's
    // 64 cs rows. acc[mi][nj][r]: n = nbase + wr*64 + mi*16 + q*4 + r
    // (IN-LANE over mi,r, ascending), m = prow0 + wc*64 + nj*16 + cl.
    float cn16[4][4];
#pragma unroll
    for (int mi = 0; mi < 4; ++mi)
#pragma unroll
        for (int r = 0; r < 4; ++r)
            cn16[mi][r] = cnorm[nbase + wr * 64 + mi * 16 + q * 4 + r];

    const int nb_lane = nbase + wr * 64 + q * 4;
#pragma unroll
    for (int nj = 0; nj < 4; ++nj) {
        float v = 3.4e38f; int idx = 0x7fffffff;
#pragma unroll
        for (int mi = 0; mi < 4; ++mi)
#pragma unroll
            for (int r = 0; r < 4; ++r) {
                float d = cn16[mi][r] - 2.f * acc[mi][nj][r];
                if (d < v) { v = d; idx = nb_lane + mi * 16 + r; }
            }
        // cross-q reduce: lane bits 4,5
#pragma unroll
        for (int mk = 16; mk <= 32; mk <<= 1) {
            float v2 = __shfl_xor(v, mk, 64);
            int   i2 = __shfl_xor(idx, mk, 64);
            if (v2 < v || (v2 == v && i2 < idx)) { v = v2; idx = i2; }
        }
        if (q == 0) {
            int pl = wc * 64 + nj * 16 + cl;   // patch col within block
            smv[pl * 4 + wr] = v;
            smi[pl * 4 + wr] = idx;
        }
    }
    __syncthreads();
    if (tid < 128) {
        float v = smv[tid * 4]; int i = smi[tid * 4];
#pragma unroll
        for (int k = 1; k < 4; ++k) {   // wr ascending = cs idx ascending
            float v1 = smv[tid * 4 + k]; int i1 = smi[tid * 4 + k];
            if (v1 < v) { v = v1; i = i1; }
        }
        pvals[(size_t)(prow0 + tid) * NTILES2 + by] = v;
        pidx[(size_t)(prow0 + tid) * NTILES2 + by]  = i;
    }
}

// ---- partial-min reduce + EXACT fp32 rescore + block-level argmax -------
// partial[block] = max over the block's 4 rows of (score_bits<<32)|(~patch):
// NO atomics (R7: 1568 device atomicMax on one 64B line bounced across
// XCDs, ~65 us serialization). dnn/top9 re-scan the 12.5 KB array instead.
__global__ void reduce_rescore_kernel(const float* __restrict__ pvals,
                                      const int* __restrict__ pidx,
                                      const float* __restrict__ emb,
                                      const float* __restrict__ cs,
                                      int* __restrict__ loc,
                                      unsigned long long* __restrict__ partial) {
    __shared__ unsigned long long keys[4];
    int w = threadIdx.x >> 6, lane = threadIdx.x & 63;
    int m = blockIdx.x * 4 + w;
    float v = pvals[(size_t)m * NTILES2 + lane];
    int   i = pidx[(size_t)m * NTILES2 + lane];
#pragma unroll
    for (int mk = 1; mk <= 32; mk <<= 1) {
        float v2 = __shfl_xor(v, mk, 64);
        int   i2 = __shfl_xor(i, mk, 64);
        if (v2 < v || (v2 == v && i2 < i)) { v = v2; i = i2; }
    }
    // exact fp32 distance to the selected coreset row
    const float* a = emb + (size_t)m * D_DIM;
    const float* bp = cs + (size_t)i * D_DIM;
    float s = 0.f;
#pragma unroll
    for (int t = 0; t < D_DIM / 64; ++t) {
        float d = a[lane + t * 64] - bp[lane + t * 64];
        s += d * d;
    }
#pragma unroll
    for (int mk = 1; mk <= 32; mk <<= 1) s += __shfl_xor(s, mk, 64);
    if (lane == 0) {
        float sc = sqrtf(s);
        loc[m] = i;
        int p = m % P_PATCH;
        keys[w] = ((unsigned long long)__float_as_uint(sc) << 32) |
                  (unsigned)(0x7fffffff - p);
    }
    __syncthreads();
    if (threadIdx.x == 0) {
        unsigned long long k = keys[0];
        if (keys[1] > k) k = keys[1];
        if (keys[2] > k) k = keys[2];
        if (keys[3] > k) k = keys[3];
        partial[blockIdx.x] = k;
    }
}

// -------------------- d_nn: 8 queries x 16384 coreset (coalesced GEMV) ----
__global__ void dnn_kernel(const float* __restrict__ cs,
                           const float* __restrict__ cnorm,
                           const unsigned long long* __restrict__ partial,
                           const int* __restrict__ loc,
                           float* __restrict__ dmat) {
    __shared__ int bnnS[BATCH];
    {   // per-block argmax recompute: 32 lanes per batch over 196 entries
        int bb = threadIdx.x >> 5, l32 = threadIdx.x & 31;
        unsigned long long best = 0ull;
        for (int j = l32; j < PBB; j += 32) {
            unsigned long long k = partial[bb * PBB + j];
            if (k > best) best = k;
        }
#pragma unroll
        for (int mk = 1; mk <= 16; mk <<= 1) {
            unsigned long long o = shfl_xor_u64(best, mk);
            if (o > best) best = o;
        }
        if (l32 == 0) {
            int p = 0x7fffffff - (unsigned)(best & 0xffffffffull);
            bnnS[bb] = loc[bb * P_PATCH + p];
        }
    }
    __syncthreads();

    int lane = threadIdx.x & 63;
    int gw = (blockIdx.x * 256 + threadIdx.x) >> 6;  // 0..1023
    float qv[BATCH][6];
#pragma unroll
    for (int b = 0; b < BATCH; ++b) {
        const float* qr = cs + (size_t)bnnS[b] * D_DIM + lane * 6;
#pragma unroll
        for (int j = 0; j < 6; ++j) qv[b][j] = qr[j];
    }
    for (int n = gw; n < N_CS; n += 1024) {
        const float* r = cs + (size_t)n * D_DIM + lane * 6;
        float x[6];
#pragma unroll
        for (int j = 0; j < 6; ++j) x[j] = r[j];
        float s[BATCH];
#pragma unroll
        for (int b = 0; b < BATCH; ++b) {
            float t = 0.f;
#pragma unroll
            for (int j = 0; j < 6; ++j) t += x[j] * qv[b][j];
            s[b] = t;
        }
#pragma unroll
        for (int b = 0; b < BATCH; ++b)
#pragma unroll
            for (int mk = 1; mk <= 32; mk <<= 1) s[b] += __shfl_xor(s[b], mk, 64);
        if (lane < BATCH) {
            float sv = s[0];
#pragma unroll
            for (int b = 1; b < BATCH; ++b) sv = (lane == b) ? s[b] : sv;
            dmat[(size_t)lane * N_CS + n] = cnorm[n] - 2.f * sv;  // -qnorm shift: order-safe
        }
    }
}

// ----------------------- top-9 merge + exact dsup + softmax weighting ----
__device__ inline void merge9(float* av, int* ai, const float* bv, const int* bi) {
    float mv[KNN]; int mi[KNN];
    int x = 0, y = 0;
#pragma unroll
    for (int k = 0; k < KNN; ++k) {
        bool ta = (av[x] < bv[y]) || (av[x] == bv[y] && ai[x] < bi[y]);
        if (ta) { mv[k] = av[x]; mi[k] = ai[x]; ++x; }
        else    { mv[k] = bv[y]; mi[k] = bi[y]; ++y; }
    }
#pragma unroll
    for (int k = 0; k < KNN; ++k) { av[k] = mv[k]; ai[k] = mi[k]; }
}

__global__ void top9_final_kernel(const float* __restrict__ dmat,
                                  const float* __restrict__ emb,
                                  const float* __restrict__ cs,
                                  const unsigned long long* __restrict__ partial,
                                  float* __restrict__ out) {
    int b = blockIdx.x;
    int tid = threadIdx.x;  // 512
    __shared__ float lv[512][KNN];
    __shared__ int   li[512][KNN];
    __shared__ float mf[D_DIM];
    __shared__ float dsup[KNN];
    __shared__ float bscoreS;
    __shared__ int   bpatchS;

    if (tid < 64) {  // argmax recompute for this batch
        unsigned long long best = 0ull;
        for (int j = tid; j < PBB; j += 64) {
            unsigned long long k = partial[b * PBB + j];
            if (k > best) best = k;
        }
#pragma unroll
        for (int mk = 1; mk <= 32; mk <<= 1) {
            unsigned long long o = shfl_xor_u64(best, mk);
            if (o > best) best = o;
        }
        if (tid == 0) {
            bpatchS = 0x7fffffff - (unsigned)(best & 0xffffffffull);
            bscoreS = __uint_as_float((unsigned)(best >> 32));
        }
    }
    __syncthreads();
    int mp = bpatchS;
    const float* frow = emb + (size_t)(b * P_PATCH + mp) * D_DIM;
    for (int i = tid; i < D_DIM; i += 512) mf[i] = frow[i];

    float tv[KNN]; int ti[KNN];
#pragma unroll
    for (int k = 0; k < KNN; ++k) { tv[k] = 3.4e38f; ti[k] = 0x7fffffff; }
    for (int n = tid; n < N_CS; n += 512) {   // ascending n per thread
        float d = dmat[(size_t)b * N_CS + n];
        if (d < tv[KNN - 1] || (d == tv[KNN - 1] && n < ti[KNN - 1])) {
            tv[KNN - 1] = d; ti[KNN - 1] = n;
#pragma unroll
            for (int k = KNN - 1; k > 0; --k) {
                if (tv[k] < tv[k - 1] || (tv[k] == tv[k - 1] && ti[k] < ti[k - 1])) {
                    float fv = tv[k]; tv[k] = tv[k - 1]; tv[k - 1] = fv;
                    int   iv = ti[k]; ti[k] = ti[k - 1]; ti[k - 1] = iv;
                }
            }
        }
    }
#pragma unroll
    for (int k = 0; k < KNN; ++k) { lv[tid][k] = tv[k]; li[tid][k] = ti[k]; }
    __syncthreads();
    for (int off = 256; off > 0; off >>= 1) {
        if (tid < off) {
            float av[KNN]; int ai[KNN]; float bv2[KNN]; int bi2[KNN];
#pragma unroll
            for (int k = 0; k < KNN; ++k) {
                av[k]  = lv[tid][k];        ai[k]  = li[tid][k];
                bv2[k] = lv[tid + off][k];  bi2[k] = li[tid + off][k];
            }
            merge9(av, ai, bv2, bi2);
#pragma unroll
            for (int k = 0; k < KNN; ++k) { lv[tid][k] = av[k]; li[tid][k] = ai[k]; }
        }
        __syncthreads();
    }
    // exact fp32 distances to the 9 support rows: 32 lanes per neighbor
    {
        int k      = tid >> 5;   // 0..15
        int lane32 = tid & 31;
        if (k < KNN) {
            int idx = li[0][k];
            const float* r = cs + (size_t)idx * D_DIM;
            float s = 0.f;
            for (int i = lane32; i < D_DIM; i += 32) {
                float df = mf[i] - r[i];
                s += df * df;
            }
#pragma unroll
            for (int mk = 1; mk <= 16; mk <<= 1) s += __shfl_xor(s, mk, 64);
            if (lane32 == 0) dsup[k] = sqrtf(fmaxf(s, 0.f));
        }
    }
    __syncthreads();
    if (tid == 0) {
        float mx = dsup[0];
        for (int k = 1; k < KNN; ++k) mx = fmaxf(mx, dsup[k]);
        float sum = 0.f, e0 = 0.f;
        for (int k = 0; k < KNN; ++k) {
            float e = expf(dsup[k] - mx);
            sum += e;
            if (k == 0) e0 = e;
        }
        out[b] = (1.f - e0 / sum) * bscoreS;
    }
}

// ------------------------------------------------------------- launcher ----
extern "C" void kernel_launch(void* const* d_in, const int* in_sizes, int n_in,
                              void* d_out, int out_size, void* d_ws, size_t ws_size,
                              hipStream_t stream) {
    (void)in_sizes; (void)n_in; (void)out_size; (void)ws_size;
    const float* emb = (const float*)d_in[0];
    const float* cs  = (const float*)d_in[1];
    float* out = (float*)d_out;

    // workspace layout (~21 MB)
    char* p = (char*)d_ws;
    float* cnorm  = (float*)p;  p += (size_t)N_CS * 4;                     // 64 KB
    float* pvals  = (float*)p;  p += (size_t)M_TOTAL * NTILES2 * 4;        // 1.6 MB
    int*   pidx   = (int*)p;    p += (size_t)M_TOTAL * NTILES2 * 4;        // 1.6 MB
    int*   loc    = (int*)p;    p += (size_t)M_TOTAL * 4;
    p = (char*)(((size_t)p + 7) & ~(size_t)7);
    unsigned long long* partial = (unsigned long long*)p; p += NBLK * 8;   // 12.5 KB
    float* dmat   = (float*)p;  p += (size_t)BATCH * N_CS * 4;             // 512 KB
    p = (char*)(((size_t)p + 15) & ~(size_t)15);
    _Float16* embh = (_Float16*)p; p += (size_t)M_TOTAL * D_DIM * 2;       // 4.8 MB
    _Float16* csh  = (_Float16*)p; p += (size_t)N_CS * D_DIM * 2;          // 12.6 MB

    {
        int rows = N_CS + M_TOTAL;
        convert_all_kernel<<<(rows + 3) / 4, 256, 0, stream>>>(emb, cs, embh, csh, cnorm);
    }
    mindist_mfma_kernel<<<MTILES * NTILES2, 512, 0, stream>>>(embh, csh, cnorm,
                                                              pvals, pidx);
    reduce_rescore_kernel<<<NBLK, 256, 0, stream>>>(pvals, pidx, emb, cs, loc, partial);
    dnn_kernel<<<256, 256, 0, stream>>>(cs, cnorm, partial, loc, dmat);
    top9_final_kernel<<<BATCH, 512, 0, stream>>>(dmat, emb, cs, partial, out);
}